// Round 4
// baseline (14803.011 us; speedup 1.0000x reference)
//
#include <hip/hip_runtime.h>
#include <math.h>

static constexpr int NB  = 1024;
static constexpr int NS  = 100;
static constexpr int NH  = 128;
static constexpr int GPB = 2;           // batches per block
static constexpr int NTHR = 256;
static constexpr int NBLK = NB / GPB;   // 512 blocks, 2/CU

static constexpr int OUT_MU = 0;
static constexpr int OUT_LV = NB * NS;
static constexpr int OUT_Z  = 2 * NB * NS;
static constexpr int OUT_TI = 3 * NB * NS;
static constexpr int OUT_LP = 4 * NB * NS;

#define NEGF (-3.4e38f)

// Fused 3-row x 2-batch f32 dot: X read as float4 (once), 3 weight rows.
// Per-accumulator fmaf chain is k-ascending — bitwise identical to R9 chains.
template<int C4>
__device__ __forceinline__ void dot2x3f(const float* __restrict__ wr0,
        const float* __restrict__ wr1, const float* __restrict__ wr2,
        const float* __restrict__ x0, const float* __restrict__ x1,
        float& r00, float& r01, float& r10, float& r11, float& r20, float& r21)
{
    const float4* W0 = reinterpret_cast<const float4*>(wr0);
    const float4* W1 = reinterpret_cast<const float4*>(wr1);
    const float4* W2 = reinterpret_cast<const float4*>(wr2);
    const float4* X0 = reinterpret_cast<const float4*>(x0);
    const float4* X1 = reinterpret_cast<const float4*>(x1);
    float a00 = 0.f, a01 = 0.f, a10 = 0.f, a11 = 0.f, a20 = 0.f, a21 = 0.f;
    #pragma unroll 8
    for (int c = 0; c < C4; ++c) {
        float4 u0 = W0[c], u1 = W1[c], u2 = W2[c];
        float4 v0 = X0[c], v1 = X1[c];
        a00 = fmaf(u0.x, v0.x, a00); a00 = fmaf(u0.y, v0.y, a00); a00 = fmaf(u0.z, v0.z, a00); a00 = fmaf(u0.w, v0.w, a00);
        a01 = fmaf(u0.x, v1.x, a01); a01 = fmaf(u0.y, v1.y, a01); a01 = fmaf(u0.z, v1.z, a01); a01 = fmaf(u0.w, v1.w, a01);
        a10 = fmaf(u1.x, v0.x, a10); a10 = fmaf(u1.y, v0.y, a10); a10 = fmaf(u1.z, v0.z, a10); a10 = fmaf(u1.w, v0.w, a10);
        a11 = fmaf(u1.x, v1.x, a11); a11 = fmaf(u1.y, v1.y, a11); a11 = fmaf(u1.z, v1.z, a11); a11 = fmaf(u1.w, v1.w, a11);
        a20 = fmaf(u2.x, v0.x, a20); a20 = fmaf(u2.y, v0.y, a20); a20 = fmaf(u2.z, v0.z, a20); a20 = fmaf(u2.w, v0.w, a20);
        a21 = fmaf(u2.x, v1.x, a21); a21 = fmaf(u2.y, v1.y, a21); a21 = fmaf(u2.z, v1.z, a21); a21 = fmaf(u2.w, v1.w, a21);
    }
    r00 = a00; r01 = a01; r10 = a10; r11 = a11; r20 = a20; r21 = a21;
}

// f64-accum dot (mu/lv epilogue) — R9 verbatim.
template<int C4>
__device__ __forceinline__ double dotwd(const float* __restrict__ w, const float* __restrict__ x)
{
    const float4* W = reinterpret_cast<const float4*>(w);
    double a = 0.0;
    #pragma unroll 8
    for (int c = 0; c < C4; ++c) {
        float4 u = W[c];
        const float* p = x + 4 * c;
        a = fma((double)u.x, (double)p[0], a);
        a = fma((double)u.y, (double)p[1], a);
        a = fma((double)u.z, (double)p[2], a);
        a = fma((double)u.w, (double)p[3], a);
    }
    return a;
}

// GRU nonlinearity (f64 internals, f32 storage) — R9 verbatim.
__device__ __forceinline__ void gruc(const float* __restrict__ bih, const float* __restrict__ bhh,
        const float* __restrict__ pa, const float* __restrict__ pb, float* __restrict__ h, int j)
{
    double r = 1.0 / (1.0 + exp(-(((double)pa[j]        + (double)bih[j])        + ((double)pb[j]        + (double)bhh[j]))));
    double z = 1.0 / (1.0 + exp(-(((double)pa[NH + j]   + (double)bih[NH + j])   + ((double)pb[NH + j]   + (double)bhh[NH + j]))));
    double n = tanh(((double)pa[2*NH + j] + (double)bih[2*NH + j]) + r * ((double)pb[2*NH + j] + (double)bhh[2*NH + j]));
    h[j] = (float)((1.0 - z) * n + z * (double)h[j]);
}

__global__ __launch_bounds__(NTHR) void vae_v15(
    const float* __restrict__ instance, const int* __restrict__ sol1,
    const int* __restrict__ sol2, const float* __restrict__ eps,
    const float* __restrict__ emb_i_W, const float* __restrict__ emb_i_b,
    const float* __restrict__ emb_r_W, const float* __restrict__ emb_r_b,
    const float* __restrict__ attn_W, const float* __restrict__ attn_v,
    const float* __restrict__ gru_Wih, const float* __restrict__ gru_Whh,
    const float* __restrict__ gru_bih, const float* __restrict__ gru_bhh,
    const float* __restrict__ grud_Wih, const float* __restrict__ grud_Whh,
    const float* __restrict__ grud_bih, const float* __restrict__ grud_bhh,
    const float* __restrict__ efc1_W, const float* __restrict__ efc1_b,
    const float* __restrict__ efc2_W, const float* __restrict__ efc2_b,
    const float* __restrict__ ptr_W, const float* __restrict__ ptr_v,
    const float* __restrict__ pfc1_W, const float* __restrict__ pfc1_b,
    const float* __restrict__ pfc2_W, const float* __restrict__ pfc2_b,
    float* __restrict__ out)
{
    __shared__ float  s_x[GPB][360];            // enc: [ref|ctx]; Z lives at [128..227]
    __shared__ float  s_h1[GPB][NH], s_h2[GPB][NH];
    __shared__ float  s_pa[GPB][3 * NH], s_pb[GPB][3 * NH];
    __shared__ double s_qh[GPB][NH];            // enc combined q (f64)
    __shared__ double s_qpA[GPB][NH], s_qpB[GPB][NH];  // enc q k-split partials
    __shared__ double2 dAa[NH], dAp[NH];        // packed (A0,A1) collapse tables (f64)
    __shared__ double dAba[NH], dAbp[NH];       // bias collapse (f64)
    __shared__ float  s_lg[GPB][NS], s_a[GPB][NS];
    __shared__ float  s_c0[GPB][NS], s_c1[GPB][NS];
    __shared__ float  t_wi0[NH], t_wi1[NH], t_bi[NH];
    __shared__ float  t_wr0[NH], t_wr1[NH], t_br[NH];
    __shared__ float  t_va[NH], t_vp[NH];
    __shared__ float  t_gbih[3*NH], t_gbhh[3*NH], t_dbih[3*NH], t_dbhh[3*NH];
    __shared__ float  t_p1b[256], t_p2b[NH];
    __shared__ int    s_sol1[GPB][NS], s_sol2[GPB][NS];
    __shared__ double s_redd[GPB][2];           // enc wave f64 sum partials
    __shared__ float  s_rc0[GPB], s_rc1[GPB];
    // ---- decoder restructure ----
    __shared__ float    s_ref[GPB][NH];         // GRU1 x-input (precomputable)
    __shared__ float    h1buf[8][GPB][NH];      // h1 snapshots per chunk
    __shared__ float    rcb0[GPB][9], rcb1[GPB][9];
    __shared__ unsigned maskb[8][GPB][4];       // mask bitmap snapshots
    __shared__ unsigned m_run[GPB][4];          // running mask bitmap
    __shared__ double   w_qh[4][NH];            // per-wave scratch
    __shared__ float    w_lg[4][NS];
    __shared__ float    w_av[4][NS];
    __shared__ float    w_x[4][360];
    __shared__ float    w_fh[4][256];
    __shared__ float    w_fo[4][NH];

    const int tid = threadIdx.x;
    const int bbase = blockIdx.x * GPB;
    const int j = tid & (NH - 1);
    const int half = tid >> 7;
    const int g = half;
    const int lane = tid & 63;
    const int wid = (tid >> 6) & 1;
    const int wv = tid >> 6;                    // wave 0..3

    // ---------- init ----------
    if (tid < NH) {
        t_wi0[tid] = emb_i_W[2*tid]; t_wi1[tid] = emb_i_W[2*tid+1]; t_bi[tid] = emb_i_b[tid];
        t_wr0[tid] = emb_r_W[2*tid]; t_wr1[tid] = emb_r_W[2*tid+1]; t_br[tid] = emb_r_b[tid];
        t_va[tid] = attn_v[tid]; t_vp[tid] = ptr_v[tid];
        t_p2b[tid] = pfc2_b[tid];
    }
    t_p1b[tid] = pfc1_b[tid];
    for (int i = tid; i < 3 * NH; i += NTHR) {
        t_gbih[i] = gru_bih[i]; t_gbhh[i] = gru_bhh[i];
        t_dbih[i] = grud_bih[i]; t_dbhh[i] = grud_bhh[i];
    }
    for (int i = tid; i < GPB * NS; i += NTHR) {
        int gg = i / NS, s = i - gg * NS;
        s_c0[gg][s] = instance[(size_t)((bbase + gg) * NS + s) * 2 + 0];
        s_c1[gg][s] = instance[(size_t)((bbase + gg) * NS + s) * 2 + 1];
        s_sol1[gg][s] = sol1[(bbase + gg) * NS + s];
        s_sol2[gg][s] = sol2[(bbase + gg) * NS + s];
    }
    s_h1[g][j] = 0.f;
    s_h2[g][j] = 0.f;
    __syncthreads();
    {   // collapse tables: f64 exact algebra (R9 verbatim)
        const float* Wm = (half == 0) ? attn_W : ptr_W;
        double a0 = 0.0, a1 = 0.0, ab = 0.0;
        for (int k = 0; k < NH; ++k) {
            double wv2 = (double)Wm[(size_t)k * NH + j];
            a0 = fma((double)t_wi0[k], wv2, a0);
            a1 = fma((double)t_wi1[k], wv2, a1);
            ab = fma((double)t_bi[k],  wv2, ab);
        }
        if (half == 0) { dAa[j].x = a0; dAa[j].y = a1; dAba[j] = ab; }
        else           { dAp[j].x = a0; dAp[j].y = a1; dAbp[j] = ab; }
    }
    {   // initial encoder ref_h
        int sp = s_sol1[g][0];
        s_x[g][j] = fmaf(s_c0[g][sp], t_wr0[j], fmaf(s_c1[g][sp], t_wr1[j], t_br[j]));
    }
    __syncthreads();

    // ---------- encoder (v14 verbatim) ----------
    for (int t = 1; t < NS; ++t) {
        if (half == 0) {
            float a00,a01,a10,a11,a20,a21;
            dot2x3f<32>(gru_Wih + (size_t)j * NH, gru_Wih + (size_t)(NH + j) * NH,
                        gru_Wih + (size_t)(2*NH + j) * NH, s_x[0], s_x[1],
                        a00,a01,a10,a11,a20,a21);
            s_pa[0][j] = a00;        s_pa[1][j] = a01;
            s_pa[0][NH + j] = a10;   s_pa[1][NH + j] = a11;
            s_pa[0][2*NH + j] = a20; s_pa[1][2*NH + j] = a21;
        } else {
            float a00,a01,a10,a11,a20,a21;
            dot2x3f<32>(gru_Whh + (size_t)j * NH, gru_Whh + (size_t)(NH + j) * NH,
                        gru_Whh + (size_t)(2*NH + j) * NH, s_h1[0], s_h1[1],
                        a00,a01,a10,a11,a20,a21);
            s_pb[0][j] = a00;        s_pb[1][j] = a01;
            s_pb[0][NH + j] = a10;   s_pb[1][NH + j] = a11;
            s_pb[0][2*NH + j] = a20; s_pb[1][2*NH + j] = a21;
        }
        __syncthreads();
        gruc(t_gbih, t_gbhh, s_pa[g], s_pb[g], s_h1[g], j);
        __syncthreads();
        {   // q k-split
            const float* col = attn_W + (size_t)NH * NH + j;
            const int k0 = half * 64;
            double a00=0.0,a01=0.0,a02=0.0,a03=0.0;
            double a10=0.0,a11=0.0,a12=0.0,a13=0.0;
            #pragma unroll 8
            for (int k = 0; k < 64; k += 4) {
                float w0 = col[(size_t)(k0+k+0) * NH];
                float w1 = col[(size_t)(k0+k+1) * NH];
                float w2 = col[(size_t)(k0+k+2) * NH];
                float w3 = col[(size_t)(k0+k+3) * NH];
                float4 h0 = *reinterpret_cast<const float4*>(&s_h1[0][k0+k]);
                float4 h1v = *reinterpret_cast<const float4*>(&s_h1[1][k0+k]);
                a00 = fma((double)w0, (double)h0.x, a00);
                a01 = fma((double)w1, (double)h0.y, a01);
                a02 = fma((double)w2, (double)h0.z, a02);
                a03 = fma((double)w3, (double)h0.w, a03);
                a10 = fma((double)w0, (double)h1v.x, a10);
                a11 = fma((double)w1, (double)h1v.y, a11);
                a12 = fma((double)w2, (double)h1v.z, a12);
                a13 = fma((double)w3, (double)h1v.w, a13);
            }
            if (half == 0) { s_qpA[0][j] = (a00+a01)+(a02+a03); s_qpA[1][j] = (a10+a11)+(a12+a13); }
            else           { s_qpB[0][j] = (a00+a01)+(a02+a03); s_qpB[1][j] = (a10+a11)+(a12+a13); }
        }
        __syncthreads();
        s_qh[g][j] = dAba[j] + (s_qpA[g][j] + s_qpB[g][j]);
        __syncthreads();
        if (j < NS) {   // relu head
            double c00 = (double)s_c0[g][j], c10 = (double)s_c1[g][j];
            double acc0 = 0.0, acc1 = 0.0, acc2 = 0.0, acc3 = 0.0;
            #pragma unroll 4
            for (int h = 0; h < NH; h += 4) {
                double2 A0 = dAa[h+0], A1 = dAa[h+1], A2 = dAa[h+2], A3 = dAa[h+3];
                double p0 = fma(c00, A0.x, fma(c10, A0.y, s_qh[g][h+0]));
                double p1 = fma(c00, A1.x, fma(c10, A1.y, s_qh[g][h+1]));
                double p2 = fma(c00, A2.x, fma(c10, A2.y, s_qh[g][h+2]));
                double p3 = fma(c00, A3.x, fma(c10, A3.y, s_qh[g][h+3]));
                acc0 = fma(fmax(p0, 0.0), (double)t_va[h+0], acc0);
                acc1 = fma(fmax(p1, 0.0), (double)t_va[h+1], acc1);
                acc2 = fma(fmax(p2, 0.0), (double)t_va[h+2], acc2);
                acc3 = fma(fmax(p3, 0.0), (double)t_va[h+3], acc3);
            }
            s_lg[g][j] = (float)(((acc0 + acc1) + (acc2 + acc3)));
        }
        __syncthreads();
        {   // fused wave softmax
            float a = s_lg[g][lane];
            float b = (lane + 64 < NS) ? s_lg[g][lane + 64] : NEGF;
            float m = fmaxf(a, b);
            m = fmaxf(m, __shfl_xor(m, 32)); m = fmaxf(m, __shfl_xor(m, 16));
            m = fmaxf(m, __shfl_xor(m, 8));  m = fmaxf(m, __shfl_xor(m, 4));
            m = fmaxf(m, __shfl_xor(m, 2));  m = fmaxf(m, __shfl_xor(m, 1));
            float fv = 0.f;
            if (j < NS) { fv = (float)exp((double)s_lg[g][j] - (double)m); s_a[g][j] = fv; }
            double ps = (double)fv;
            ps += __shfl_xor(ps, 32); ps += __shfl_xor(ps, 16);
            ps += __shfl_xor(ps, 8);  ps += __shfl_xor(ps, 4);
            ps += __shfl_xor(ps, 2);  ps += __shfl_xor(ps, 1);
            if (lane == 0) s_redd[g][wid] = ps;
        }
        __syncthreads();
        if (j < NS) {
            double se = s_redd[g][0] + s_redd[g][1];
            s_a[g][j] = (float)((double)s_a[g][j] / se);
        }
        __syncthreads();
        {   // context + new ref_h
            float w0 = t_wi0[j], w1 = t_wi1[j], bb = t_bi[j];
            double a0 = 0.0, a1 = 0.0, a2 = 0.0, a3 = 0.0;
            #pragma unroll 5
            for (int s = 0; s < NS; s += 4) {
                float ih0 = fmaf(s_c0[g][s+0], w0, fmaf(s_c1[g][s+0], w1, bb));
                float ih1 = fmaf(s_c0[g][s+1], w0, fmaf(s_c1[g][s+1], w1, bb));
                float ih2 = fmaf(s_c0[g][s+2], w0, fmaf(s_c1[g][s+2], w1, bb));
                float ih3 = fmaf(s_c0[g][s+3], w0, fmaf(s_c1[g][s+3], w1, bb));
                a0 += (double)s_a[g][s+0] * (double)ih0;
                a1 += (double)s_a[g][s+1] * (double)ih1;
                a2 += (double)s_a[g][s+2] * (double)ih2;
                a3 += (double)s_a[g][s+3] * (double)ih3;
            }
            s_x[g][NH + j] = (float)(((a0 + a1) + (a2 + a3)));
            int sp = s_sol1[g][t];
            s_x[g][j] = fmaf(s_c0[g][sp], t_wr0[j], fmaf(s_c1[g][sp], t_wr1[j], t_br[j]));
        }
        __syncthreads();
        if (half == 0) {
            float a00,a01,a10,a11,a20,a21;
            dot2x3f<64>(grud_Wih + (size_t)j * 256, grud_Wih + (size_t)(NH + j) * 256,
                        grud_Wih + (size_t)(2*NH + j) * 256, s_x[0], s_x[1],
                        a00,a01,a10,a11,a20,a21);
            s_pa[0][j] = a00;        s_pa[1][j] = a01;
            s_pa[0][NH + j] = a10;   s_pa[1][NH + j] = a11;
            s_pa[0][2*NH + j] = a20; s_pa[1][2*NH + j] = a21;
        } else {
            float a00,a01,a10,a11,a20,a21;
            dot2x3f<32>(grud_Whh + (size_t)j * NH, grud_Whh + (size_t)(NH + j) * NH,
                        grud_Whh + (size_t)(2*NH + j) * NH, s_h2[0], s_h2[1],
                        a00,a01,a10,a11,a20,a21);
            s_pb[0][j] = a00;        s_pb[1][j] = a01;
            s_pb[0][NH + j] = a10;   s_pb[1][NH + j] = a11;
            s_pb[0][2*NH + j] = a20; s_pb[1][2*NH + j] = a21;
        }
        __syncthreads();
        gruc(t_dbih, t_dbhh, s_pa[g], s_pb[g], s_h2[g], j);
        __syncthreads();
    }

    // ---------- epilogue: mu, lv, Z ----------
    for (int idx = tid; idx < GPB * NS; idx += NTHR) {
        int gg = idx / NS, s = idx - gg * NS, b = bbase + gg;
        double mu = dotwd<32>(efc1_W + (size_t)s * NH, s_h2[gg]) + (double)efc1_b[s];
        double lv = dotwd<32>(efc2_W + (size_t)s * NH, s_h2[gg]) + (double)efc2_b[s];
        double z  = mu + (double)eps[(size_t)b * NS + s] * exp(0.5 * lv);
        out[OUT_MU + b * NS + s] = (float)mu;
        out[OUT_LV + b * NS + s] = (float)lv;
        out[OUT_Z  + b * NS + s] = (float)z;
        s_x[gg][NH + s] = (float)z;   // decoder Z slot [128..227]
    }
    s_h1[g][j] = 0.f;
    __syncthreads();
    if (tid < GPB) {
        int b = bbase + tid;
        int s0 = s_sol2[tid][0];
        m_run[tid][0] = 0xFFFFFFFFu; m_run[tid][1] = 0xFFFFFFFFu;
        m_run[tid][2] = 0xFFFFFFFFu; m_run[tid][3] = 0xFu;
        m_run[tid][s0 >> 5] &= ~(1u << (s0 & 31));
        s_rc0[tid] = s_c0[tid][s0];
        s_rc1[tid] = s_c1[tid][s0];
        out[OUT_TI + b * NS + 0] = (float)s0;
    }
    __syncthreads();
    // initial ref for t=1
    s_ref[g][j] = fmaf(s_rc0[g], t_wr0[j], fmaf(s_rc1[g], t_wr1[j], t_br[j]));
    __syncthreads();

    // ---------- decoder: chunked serial-GRU + wave-parallel heads ----------
    for (int c = 0; c < 13; ++c) {
        const int t0 = 1 + c * 8;
        const int CHc = (t0 + 8 <= NS) ? 8 : (NS - t0);
        if (tid < GPB) {    // pre-phase: mask snapshots + ref coords (data-independent)
            const int gg = tid;
            for (int qi = 0; qi <= CHc; ++qi) {
                int tt = t0 + qi;
                if (qi < CHc) {
                    maskb[qi][gg][0] = m_run[gg][0];
                    maskb[qi][gg][1] = m_run[gg][1];
                    maskb[qi][gg][2] = m_run[gg][2];
                    maskb[qi][gg][3] = m_run[gg][3];
                    int pt = s_sol2[gg][tt];
                    m_run[gg][pt >> 5] &= ~(1u << (pt & 31));
                }
                int sp = s_sol2[gg][tt - 1];
                rcb0[gg][qi] = s_c0[gg][sp];
                rcb1[gg][qi] = s_c1[gg][sp];
            }
        }
        __syncthreads();
        // ---- D1: minimal serial GRU1 recurrence ----
        for (int q = 0; q < CHc; ++q) {
            if (half == 0) {
                float a00,a01,a10,a11,a20,a21;
                dot2x3f<32>(gru_Wih + (size_t)j * NH, gru_Wih + (size_t)(NH + j) * NH,
                            gru_Wih + (size_t)(2*NH + j) * NH, s_ref[0], s_ref[1],
                            a00,a01,a10,a11,a20,a21);
                s_pa[0][j] = a00;        s_pa[1][j] = a01;
                s_pa[0][NH + j] = a10;   s_pa[1][NH + j] = a11;
                s_pa[0][2*NH + j] = a20; s_pa[1][2*NH + j] = a21;
            } else {
                float a00,a01,a10,a11,a20,a21;
                dot2x3f<32>(gru_Whh + (size_t)j * NH, gru_Whh + (size_t)(NH + j) * NH,
                            gru_Whh + (size_t)(2*NH + j) * NH, s_h1[0], s_h1[1],
                            a00,a01,a10,a11,a20,a21);
                s_pb[0][j] = a00;        s_pb[1][j] = a01;
                s_pb[0][NH + j] = a10;   s_pb[1][NH + j] = a11;
                s_pb[0][2*NH + j] = a20; s_pb[1][2*NH + j] = a21;
            }
            __syncthreads();
            gruc(t_gbih, t_gbhh, s_pa[g], s_pb[g], s_h1[g], j);
            h1buf[q][g][j] = s_h1[g][j];
            s_ref[g][j] = fmaf(rcb0[g][q+1], t_wr0[j], fmaf(rcb1[g][q+1], t_wr1[j], t_br[j]));
            __syncthreads();
        }
        // ---- D2: one (batch,t) task per wave, barrier-free ----
        for (int task = wv; task < 2 * CHc; task += 4) {
            const int gg = task & 1;
            const int qq = task >> 1;
            const int tt = t0 + qq;
            double* qh = w_qh[wv];
            float*  lg = w_lg[wv];
            float*  av = w_av[wv];
            float*  xx = w_x[wv];
            float*  fh = w_fh[wv];
            float*  fo = w_fo[wv];
            const float* h1t = &h1buf[qq][gg][0];
            // attn q
            #pragma unroll
            for (int p = 0; p < 2; ++p) {
                const int jj = lane + (p << 6);
                const float* col = attn_W + (size_t)NH * NH + jj;
                double a0=0.0,a1=0.0,a2=0.0,a3=0.0;
                #pragma unroll 8
                for (int k = 0; k < NH; k += 4) {
                    a0 = fma((double)col[(size_t)(k+0)*NH], (double)h1t[k+0], a0);
                    a1 = fma((double)col[(size_t)(k+1)*NH], (double)h1t[k+1], a1);
                    a2 = fma((double)col[(size_t)(k+2)*NH], (double)h1t[k+2], a2);
                    a3 = fma((double)col[(size_t)(k+3)*NH], (double)h1t[k+3], a3);
                }
                qh[jj] = dAba[jj] + ((a0+a1)+(a2+a3));
            }
            // relu head
            #pragma unroll
            for (int p = 0; p < 2; ++p) {
                const int jj = lane + (p << 6);
                if (jj < NS) {
                    double c00 = (double)s_c0[gg][jj], c10 = (double)s_c1[gg][jj];
                    double acc0=0.0,acc1=0.0,acc2=0.0,acc3=0.0;
                    #pragma unroll 4
                    for (int h = 0; h < NH; h += 4) {
                        double2 A0=dAa[h+0],A1=dAa[h+1],A2=dAa[h+2],A3=dAa[h+3];
                        double p0 = fma(c00,A0.x,fma(c10,A0.y,qh[h+0]));
                        double p1 = fma(c00,A1.x,fma(c10,A1.y,qh[h+1]));
                        double p2 = fma(c00,A2.x,fma(c10,A2.y,qh[h+2]));
                        double p3 = fma(c00,A3.x,fma(c10,A3.y,qh[h+3]));
                        acc0 = fma(fmax(p0,0.0),(double)t_va[h+0],acc0);
                        acc1 = fma(fmax(p1,0.0),(double)t_va[h+1],acc1);
                        acc2 = fma(fmax(p2,0.0),(double)t_va[h+2],acc2);
                        acc3 = fma(fmax(p3,0.0),(double)t_va[h+3],acc3);
                    }
                    lg[jj] = (float)((acc0+acc1)+(acc2+acc3));
                }
            }
            // softmax1 + normalize (wave-local)
            {
                float v1 = lg[lane];
                float v2 = (lane + 64 < NS) ? lg[lane + 64] : NEGF;
                float m = fmaxf(v1, v2);
                m = fmaxf(m, __shfl_xor(m,32)); m = fmaxf(m, __shfl_xor(m,16));
                m = fmaxf(m, __shfl_xor(m,8));  m = fmaxf(m, __shfl_xor(m,4));
                m = fmaxf(m, __shfl_xor(m,2));  m = fmaxf(m, __shfl_xor(m,1));
                float f1 = (float)exp((double)v1 - (double)m);
                float f2 = 0.f;
                if (lane + 64 < NS) f2 = (float)exp((double)v2 - (double)m);
                double ps = (double)f1 + (double)f2;
                ps += __shfl_xor(ps,32); ps += __shfl_xor(ps,16); ps += __shfl_xor(ps,8);
                ps += __shfl_xor(ps,4);  ps += __shfl_xor(ps,2);  ps += __shfl_xor(ps,1);
                av[lane] = (float)((double)f1 / ps);
                if (lane + 64 < NS) av[lane + 64] = (float)((double)f2 / ps);
            }
            // context -> xx[0..127]
            #pragma unroll
            for (int p = 0; p < 2; ++p) {
                const int jj = lane + (p << 6);
                float w0 = t_wi0[jj], w1 = t_wi1[jj], bb2 = t_bi[jj];
                double a0=0.0,a1=0.0,a2=0.0,a3=0.0;
                #pragma unroll 5
                for (int s = 0; s < NS; s += 4) {
                    float ih0 = fmaf(s_c0[gg][s+0], w0, fmaf(s_c1[gg][s+0], w1, bb2));
                    float ih1 = fmaf(s_c0[gg][s+1], w0, fmaf(s_c1[gg][s+1], w1, bb2));
                    float ih2 = fmaf(s_c0[gg][s+2], w0, fmaf(s_c1[gg][s+2], w1, bb2));
                    float ih3 = fmaf(s_c0[gg][s+3], w0, fmaf(s_c1[gg][s+3], w1, bb2));
                    a0 += (double)av[s+0] * (double)ih0;
                    a1 += (double)av[s+1] * (double)ih1;
                    a2 += (double)av[s+2] * (double)ih2;
                    a3 += (double)av[s+3] * (double)ih3;
                }
                xx[jj] = (float)((a0+a1)+(a2+a3));
            }
            // Z copy + ref into xx
            {
                xx[NH + lane] = s_x[gg][NH + lane];
                if (lane + 64 < NS) xx[NH + lane + 64] = s_x[gg][NH + lane + 64];
                float rc0v = rcb0[gg][qq], rc1v = rcb1[gg][qq];
                xx[228 + lane]      = fmaf(rc0v, t_wr0[lane],      fmaf(rc1v, t_wr1[lane],      t_br[lane]));
                xx[228 + lane + 64] = fmaf(rc0v, t_wr0[lane + 64], fmaf(rc1v, t_wr1[lane + 64], t_br[lane + 64]));
            }
            // pfc1 (R9 chain per row)
            #pragma unroll
            for (int p = 0; p < 4; ++p) {
                const int i = lane + (p << 6);
                const float4* W = reinterpret_cast<const float4*>(pfc1_W + (size_t)i * 356);
                float a0 = 0.f;
                #pragma unroll 8
                for (int c4 = 0; c4 < 89; ++c4) {
                    float4 u = W[c4];
                    const int k = 4 * c4;
                    a0 = fmaf(u.x, xx[k+0], a0); a0 = fmaf(u.y, xx[k+1], a0);
                    a0 = fmaf(u.z, xx[k+2], a0); a0 = fmaf(u.w, xx[k+3], a0);
                }
                fh[i] = a0 + t_p1b[i];
            }
            // pfc2
            #pragma unroll
            for (int p = 0; p < 2; ++p) {
                const int jj = lane + (p << 6);
                const float4* W = reinterpret_cast<const float4*>(pfc2_W + (size_t)jj * 256);
                float a0 = 0.f;
                #pragma unroll 8
                for (int c4 = 0; c4 < 64; ++c4) {
                    float4 u = W[c4];
                    const int k = 4 * c4;
                    a0 = fmaf(u.x, fh[k+0], a0); a0 = fmaf(u.y, fh[k+1], a0);
                    a0 = fmaf(u.z, fh[k+2], a0); a0 = fmaf(u.w, fh[k+3], a0);
                }
                fo[jj] = a0 + t_p2b[jj];
            }
            // ptr q2 (overwrite qh)
            #pragma unroll
            for (int p = 0; p < 2; ++p) {
                const int jj = lane + (p << 6);
                const float* col = ptr_W + (size_t)NH * NH + jj;
                double a0=0.0,a1=0.0,a2=0.0,a3=0.0;
                #pragma unroll 8
                for (int k = 0; k < NH; k += 4) {
                    a0 = fma((double)col[(size_t)(k+0)*NH], (double)fo[k+0], a0);
                    a1 = fma((double)col[(size_t)(k+1)*NH], (double)fo[k+1], a1);
                    a2 = fma((double)col[(size_t)(k+2)*NH], (double)fo[k+2], a2);
                    a3 = fma((double)col[(size_t)(k+3)*NH], (double)fo[k+3], a3);
                }
                qh[jj] = dAbp[jj] + ((a0+a1)+(a2+a3));
            }
            // tanh head
            #pragma unroll
            for (int p = 0; p < 2; ++p) {
                const int jj = lane + (p << 6);
                if (jj < NS) {
                    double c00 = (double)s_c0[gg][jj], c10 = (double)s_c1[gg][jj];
                    double acc0=0.0,acc1=0.0,acc2=0.0,acc3=0.0;
                    #pragma unroll 4
                    for (int h = 0; h < NH; h += 4) {
                        double2 A0=dAp[h+0],A1=dAp[h+1],A2=dAp[h+2],A3=dAp[h+3];
                        double p0 = fma(c00,A0.x,fma(c10,A0.y,qh[h+0]));
                        double p1 = fma(c00,A1.x,fma(c10,A1.y,qh[h+1]));
                        double p2 = fma(c00,A2.x,fma(c10,A2.y,qh[h+2]));
                        double p3 = fma(c00,A3.x,fma(c10,A3.y,qh[h+3]));
                        acc0 = fma((double)tanhf((float)p0),(double)t_vp[h+0],acc0);
                        acc1 = fma((double)tanhf((float)p1),(double)t_vp[h+1],acc1);
                        acc2 = fma((double)tanhf((float)p2),(double)t_vp[h+2],acc2);
                        acc3 = fma((double)tanhf((float)p3),(double)t_vp[h+3],acc3);
                    }
                    lg[jj] = (float)((acc0+acc1)+(acc2+acc3));
                }
            }
            // softmax2 (masked) + argmax + outputs
            {
                const unsigned* mwp = &maskb[qq][gg][0];
                bool u1 = (mwp[lane >> 5] >> (lane & 31)) & 1u;
                float l1 = lg[lane];
                float c1v = u1 ? l1 : NEGF;
                bool u2 = false; float l2 = 0.f, c2v = NEGF;
                if (lane + 64 < NS) {
                    u2 = (mwp[(lane + 64) >> 5] >> (lane & 31)) & 1u;
                    l2 = lg[lane + 64];
                    c2v = u2 ? l2 : NEGF;
                }
                float m = fmaxf(c1v, c2v);
                m = fmaxf(m, __shfl_xor(m,32)); m = fmaxf(m, __shfl_xor(m,16));
                m = fmaxf(m, __shfl_xor(m,8));  m = fmaxf(m, __shfl_xor(m,4));
                m = fmaxf(m, __shfl_xor(m,2));  m = fmaxf(m, __shfl_xor(m,1));
                float f1 = u1 ? (float)exp((double)l1 - (double)m) : 0.f;
                av[lane] = f1;
                float f2 = 0.f;
                if (lane + 64 < NS) {
                    f2 = u2 ? (float)exp((double)l2 - (double)m) : 0.f;
                    av[lane + 64] = f2;
                }
                float bv = f1; int bi = lane;
                if (lane + 64 < NS && f2 > bv) { bv = f2; bi = lane + 64; }
                double ps = (double)f1 + (double)f2;
                #pragma unroll
                for (int o = 32; o >= 1; o >>= 1) {
                    float  ov = __shfl_xor(bv, o);
                    int    oi = __shfl_xor(bi, o);
                    double op = __shfl_xor(ps, o);
                    ps += op;
                    if (ov > bv || (ov == bv && oi < bi)) { bv = ov; bi = oi; }
                }
                if (lane == 0) {
                    int pt = s_sol2[gg][tt];
                    double logp = log((double)av[pt] / ps);
                    out[OUT_TI + (size_t)(bbase + gg) * NS + tt]            = (float)bi;
                    out[OUT_LP + (size_t)(bbase + gg) * (NS - 1) + (tt - 1)] = (float)logp;
                }
            }
        }
        __syncthreads();
    }
}

extern "C" void kernel_launch(void* const* d_in, const int* in_sizes, int n_in,
                              void* d_out, int out_size, void* d_ws, size_t ws_size,
                              hipStream_t stream)
{
    (void)in_sizes; (void)n_in; (void)out_size; (void)d_ws; (void)ws_size;
    vae_v15<<<NBLK, NTHR, 0, stream>>>(
        (const float*)d_in[0], (const int*)d_in[1], (const int*)d_in[2], (const float*)d_in[3],
        (const float*)d_in[4], (const float*)d_in[5], (const float*)d_in[6], (const float*)d_in[7],
        (const float*)d_in[8], (const float*)d_in[9], (const float*)d_in[10], (const float*)d_in[11],
        (const float*)d_in[12], (const float*)d_in[13], (const float*)d_in[14], (const float*)d_in[15],
        (const float*)d_in[16], (const float*)d_in[17], (const float*)d_in[18], (const float*)d_in[19],
        (const float*)d_in[20], (const float*)d_in[21], (const float*)d_in[22], (const float*)d_in[23],
        (const float*)d_in[24], (const float*)d_in[25], (const float*)d_in[26], (const float*)d_in[27],
        (float*)d_out);
}